// Round 4
// baseline (1744.982 us; speedup 1.0000x reference)
//
#include <hip/hip_runtime.h>
#include <hip/hip_fp16.h>

#define TT 2048
#define BB 64
#define HH 128
#define GG 512   // 4H
#define CH 64    // chunk (timesteps per handshake)
#define NCH (TT / CH)

typedef _Float16 f16x8 __attribute__((ext_vector_type(8)));
typedef _Float16 f16x4 __attribute__((ext_vector_type(4)));
typedef _Float16 f16x2 __attribute__((ext_vector_type(2)));
typedef float f32x4 __attribute__((ext_vector_type(4)));

__device__ __forceinline__ float sigm(float x) {
    return __builtin_amdgcn_rcpf(1.0f + __expf(-x));
}
__device__ __forceinline__ float tanh_f(float x) {
    return 1.0f - 2.0f * __builtin_amdgcn_rcpf(1.0f + __expf(2.0f * x));
}
// LDS-only barrier: no vmcnt drain (HIP __syncthreads drains all global ops).
__device__ __forceinline__ void bar_lds() {
    asm volatile("s_waitcnt lgkmcnt(0)\n\ts_barrier" ::: "memory");
}

__device__ __forceinline__ f16x8 load_frag(const float* rowp, int kt, int lh) {
    const float4* p4 = (const float4*)(rowp + kt * 32 + lh * 8);
    float4 a = p4[0], b = p4[1];
    f16x8 f;
    f[0] = (_Float16)a.x; f[1] = (_Float16)a.y; f[2] = (_Float16)a.z; f[3] = (_Float16)a.w;
    f[4] = (_Float16)b.x; f[5] = (_Float16)b.y; f[6] = (_Float16)b.z; f[7] = (_Float16)b.w;
    return f;
}

// 32-term dot over one k-quarter: Wg[0..3] x hq[0..3], f32 accumulate via
// v_dot2_f32_f16 (full-rate VALU). Two accumulator chains (8-deep) for ILP.
__device__ __forceinline__ float dot_q(const f16x8* Wg, const f16x8* hq) {
    float a = 0.f, b = 0.f;
#pragma unroll
    for (int j = 0; j < 2; ++j)
#pragma unroll
        for (int d = 0; d < 4; ++d) {
            a = __builtin_amdgcn_fdot2(
                (f16x2){Wg[j][2 * d], Wg[j][2 * d + 1]},
                (f16x2){hq[j][2 * d], hq[j][2 * d + 1]}, a, false);
            b = __builtin_amdgcn_fdot2(
                (f16x2){Wg[2 + j][2 * d], Wg[2 + j][2 * d + 1]},
                (f16x2){hq[2 + j][2 * d], hq[2 + j][2 * d + 1]}, b, false);
        }
    return a + b;
}

// Round 20: VALU-dot recurrence (MFMA only for the batched chunk GEMM).
// Model (calibrated on r16/r17/r18): old step = ~620cy/SIMD MFMA-pipe
// occupancy (128 MFMAs/step at 1/16 M-utilization = 53 useful FLOP/cy/SIMD)
// + ~220cy VALU + ~600cy serial sync, phases strictly alternating. The VALU
// dot2 path does the same 65k MACs at 128 FLOP/cy/SIMD (2.4x the useful MFMA
// rate) with no M-waste: thread (n=tid>>2, q=tid&3) holds W_hh rows
// {g*128+n}_{g=0..3} over k-quarter q in 64 VGPRs, reloads the h-quarter per
// step (4 broadcast ds_read_b128), does 64 v_dot2_f32_f16, reduces over the
// 4-lane q-group via shfl_xor, gate-chain on q==0 lanes.
// Step model: 120 read + 256 dot-issue/SIMD + 60 shfl + 104 chain + 110
// write/barrier ~= 650cy vs measured 1560 -> predict ~2x on k_pipe.
__global__ __launch_bounds__(512, 1) void k_pipe(
    const float* __restrict__ x, const int* __restrict__ lengths,
    const float* __restrict__ ff_w, const float* __restrict__ ff_b,
    const float* __restrict__ W_ih0, const float* __restrict__ W_hh0,
    const float* __restrict__ b0, const float* __restrict__ W_ih1,
    const float* __restrict__ W_hh1, const float* __restrict__ b1,
    _Float16* __restrict__ h0g, int* __restrict__ flags,
    float* __restrict__ pooled) {
    const int tid = threadIdx.x;
    const int w = tid >> 6;
    const int lane = tid & 63;
    const int c = lane & 15;
    const int lh = lane >> 4;
    const int un = 16 * w + c;     // chunk-GEMM column mapping (unchanged)
    const int n = tid >> 2;        // recurrence: output column 0..127
    const int q = tid & 3;         // recurrence: k-quarter
    const bool q0 = (q == 0);

    __shared__ float xs[TT];                 // producer
    __shared__ _Float16 Hb0[2][HH];          // producer
    __shared__ _Float16 Hb1[2][HH];          // consumer
    __shared__ _Float16 Qs[CH][GG];          // consumer: chunk gates (64 KB)

    if (blockIdx.x < BB) {
        // ======================= PRODUCER: layer 0 =======================
        const int b = blockIdx.x;
        for (int i = tid; i < TT; i += 512) xs[i] = x[b * TT + i];
        if (tid < 2 * HH) ((_Float16*)Hb0)[tid] = (_Float16)0.f;

        f16x8 Wr[4][4];  // [gate][k-octet] of W_hh0 row g*128+n, quarter q
        float v4[4], u4[4];
#pragma unroll
        for (int g = 0; g < 4; ++g) {
            const int r = g * HH + n;
#pragma unroll
            for (int j = 0; j < 4; ++j) Wr[g][j] = load_frag(W_hh0 + r * HH, q, j);
            const float4* wi4 = (const float4*)(W_ih0 + r * HH);
            const float4* fw4 = (const float4*)ff_w;
            const float4* fb4 = (const float4*)ff_b;
            float vv = 0.f, uu = 0.f;
#pragma unroll
            for (int m = 0; m < HH / 4; ++m) {
                float4 a = wi4[m], fw = fw4[m], fb = fb4[m];
                vv += a.x * fw.x + a.y * fw.y + a.z * fw.z + a.w * fw.w;
                uu += a.x * fb.x + a.y * fb.y + a.z * fb.z + a.w * fb.w;
            }
            v4[g] = vv;
            u4[g] = uu + b0[r];
        }
#pragma unroll
        for (int g = 0; g < 4; ++g)
#pragma unroll
            for (int j = 0; j < 4; ++j) asm volatile("" : "+v"(Wr[g][j]));

        float cst0 = 0.f;
        __syncthreads();

#define PSTEP(T_, RB_, XT_)                                                     \
    do {                                                                        \
        f16x8 hq[4];                                                            \
        _Pragma("unroll") for (int j = 0; j < 4; ++j)                           \
            hq[j] = *(const f16x8*)&Hb0[RB_][32 * q + 8 * j];                   \
        float p[4];                                                             \
        _Pragma("unroll") for (int g = 0; g < 4; ++g) p[g] = dot_q(Wr[g], hq);  \
        _Pragma("unroll") for (int g = 0; g < 4; ++g) {                         \
            p[g] += __shfl_xor(p[g], 1, 4);                                     \
            p[g] += __shfl_xor(p[g], 2, 4);                                     \
        }                                                                       \
        if (q0) {                                                               \
            float s0 = p[0] + (XT_) * v4[0] + u4[0];                            \
            float s1 = p[1] + (XT_) * v4[1] + u4[1];                            \
            float s2 = p[2] + (XT_) * v4[2] + u4[2];                            \
            float s3 = p[3] + (XT_) * v4[3] + u4[3];                            \
            float gi = sigm(s0), gf = sigm(s1);                                 \
            float gg = tanh_f(s2), go = sigm(s3);                               \
            cst0 = gf * cst0 + gi * gg;                                         \
            float h0n = go * tanh_f(cst0);                                      \
            Hb0[(RB_) ^ 1][n] = (_Float16)h0n;                                  \
            __builtin_nontemporal_store(                                        \
                (_Float16)h0n, h0g + ((size_t)b * TT + (T_)) * HH + n);         \
        }                                                                       \
        bar_lds();                                                              \
    } while (0)

        for (int ch = 0; ch < NCH; ++ch) {
            const int t0 = ch * CH;
            for (int j = 0; j < CH; j += 2) {
                const float xt0 = xs[t0 + j];
                const float xt1 = xs[t0 + j + 1];
                PSTEP(t0 + j, 0, xt0);
                PSTEP(t0 + j + 1, 1, xt1);
            }
            __syncthreads();  // drain every wave's h0 NT stores before signaling
            if (tid == 0)
                __hip_atomic_store(&flags[b * NCH + ch], ch + 1, __ATOMIC_RELEASE,
                                   __HIP_MEMORY_SCOPE_AGENT);
        }
#undef PSTEP
    } else {
        // ======================= CONSUMER: layer 1 =======================
        const int b = blockIdx.x - BB;
        if (tid < 2 * HH) ((_Float16*)Hb1)[tid] = (_Float16)0.f;

        f16x8 Wr[4][4];  // [gate][k-octet] of W_hh1 row g*128+n, quarter q
        float bb1[4];    // chunk-GEMM bias (un-keyed, unchanged)
#pragma unroll
        for (int g = 0; g < 4; ++g) {
            const int r = g * HH + n;
#pragma unroll
            for (int j = 0; j < 4; ++j) Wr[g][j] = load_frag(W_hh1 + r * HH, q, j);
            bb1[g] = b1[g * HH + un];
        }
#pragma unroll
        for (int g = 0; g < 4; ++g)
#pragma unroll
            for (int j = 0; j < 4; ++j) asm volatile("" : "+v"(Wr[g][j]));

        const int len = lengths[b];
        float cst1 = 0.f, mean = 0.f, mx = -1e30f, last = 0.f;
        __syncthreads();

#define CSTEP(T_, RB_, QV_)                                                     \
    do {                                                                        \
        f16x8 hq[4];                                                            \
        _Pragma("unroll") for (int j = 0; j < 4; ++j)                           \
            hq[j] = *(const f16x8*)&Hb1[RB_][32 * q + 8 * j];                   \
        float p[4];                                                             \
        _Pragma("unroll") for (int g = 0; g < 4; ++g) p[g] = dot_q(Wr[g], hq);  \
        _Pragma("unroll") for (int g = 0; g < 4; ++g) {                         \
            p[g] += __shfl_xor(p[g], 1, 4);                                     \
            p[g] += __shfl_xor(p[g], 2, 4);                                     \
        }                                                                       \
        if (q0) {                                                               \
            float s0 = p[0] + (float)(QV_)[0];                                  \
            float s1 = p[1] + (float)(QV_)[1];                                  \
            float s2 = p[2] + (float)(QV_)[2];                                  \
            float s3 = p[3] + (float)(QV_)[3];                                  \
            float gi = sigm(s0), gf = sigm(s1);                                 \
            float gg = tanh_f(s2), go = sigm(s3);                               \
            cst1 = gf * cst1 + gi * gg;                                         \
            float h1n = go * tanh_f(cst1);                                      \
            Hb1[(RB_) ^ 1][n] = (_Float16)h1n;                                  \
            if ((T_) < len) {                                                   \
                mean += h1n;                                                    \
                mx = fmaxf(mx, h1n);                                            \
            }                                                                   \
            if ((T_) == len - 1) last = h1n;                                    \
        }                                                                       \
        bar_lds();                                                              \
    } while (0)

        for (int ch = 0; ch < NCH; ++ch) {
            if (tid == 0) {  // acquire gate
                int guard = 0;
                while (__hip_atomic_load(&flags[b * NCH + ch], __ATOMIC_ACQUIRE,
                                         __HIP_MEMORY_SCOPE_AGENT) != ch + 1) {
                    __builtin_amdgcn_s_sleep(8);
                    if (++guard > (1 << 22)) break;  // hang guard
                }
            }
            __syncthreads();
            // ---- chunk GEMM (MFMA, unchanged): Qs[j][un*4+t2] ----
            f16x8 Bi[4][4];  // reloaded per chunk (keeps step-loop pressure low)
#pragma unroll
            for (int t2 = 0; t2 < 4; ++t2)
#pragma unroll
                for (int kt = 0; kt < 4; ++kt)
                    Bi[t2][kt] = load_frag(W_ih1 + (t2 * HH + un) * HH, kt, lh);
            const _Float16* hbase = h0g + ((size_t)b * TT + ch * CH) * HH;
#pragma unroll
            for (int mt = 0; mt < 4; ++mt) {
                f16x8 am[4];  // A[m=c][k=kt*32+lh*8+j]
#pragma unroll
                for (int kt = 0; kt < 4; ++kt)
                    am[kt] = *(const f16x8*)(hbase + (mt * 16 + c) * HH + kt * 32 + lh * 8);
                f32x4 qa[4];
#pragma unroll
                for (int t2 = 0; t2 < 4; ++t2) {
                    qa[t2] = (f32x4){0.f, 0.f, 0.f, 0.f};
#pragma unroll
                    for (int kt = 0; kt < 4; ++kt)
                        qa[t2] = __builtin_amdgcn_mfma_f32_16x16x32_f16(
                            am[kt], Bi[t2][kt], qa[t2], 0, 0, 0);
                }
#pragma unroll
                for (int r = 0; r < 4; ++r) {  // C row m = 4*lh + r
                    f16x4 qv;
#pragma unroll
                    for (int t2 = 0; t2 < 4; ++t2) qv[t2] = (_Float16)(qa[t2][r] + bb1[t2]);
                    *(f16x4*)&Qs[mt * 16 + 4 * lh + r][un * 4] = qv;
                }
            }
            __syncthreads();  // Qs visible to all waves
            // ---- 64 recurrence steps, gates from LDS ----
            const int t0 = ch * CH;
            for (int j = 0; j < CH; j += 2) {
                const f16x4 qv0 = *(const f16x4*)&Qs[j][n * 4];     // broadcast
                const f16x4 qv1 = *(const f16x4*)&Qs[j + 1][n * 4];
                CSTEP(t0 + j, 0, qv0);
                CSTEP(t0 + j + 1, 1, qv1);
            }
        }
#undef CSTEP
        if (q0) {
            pooled[b * 384 + n] = mean / (float)len;
            pooled[b * 384 + 128 + n] = mx;
            pooled[b * 384 + 256 + n] = last;
        }
    }
}

// ---------------- head: [B,3H] @ [3H,C]^T + bias ----------------
__global__ __launch_bounds__(448) void k_head(
    const float* __restrict__ pooled, const float* __restrict__ lin_w,
    const float* __restrict__ lin_b, float* __restrict__ out) {
    int tid = threadIdx.x;  // 448 = 64*7
    int b = tid / 7, cc = tid % 7;
    const float* p = pooled + b * 384;
    const float* wr = lin_w + cc * 384;
    float a0 = 0.f, a1 = 0.f, a2 = 0.f, a3 = 0.f;
#pragma unroll
    for (int k = 0; k < 384; k += 4) {
        a0 += p[k + 0] * wr[k + 0];
        a1 += p[k + 1] * wr[k + 1];
        a2 += p[k + 2] * wr[k + 2];
        a3 += p[k + 3] * wr[k + 3];
    }
    out[tid] = lin_b[cc] + ((a0 + a1) + (a2 + a3));
}

extern "C" void kernel_launch(void* const* d_in, const int* in_sizes, int n_in,
                              void* d_out, int out_size, void* d_ws, size_t ws_size,
                              hipStream_t stream) {
    const float* x     = (const float*)d_in[0];
    const int*   lens  = (const int*)d_in[1];
    const float* ff_w  = (const float*)d_in[2];
    const float* ff_b  = (const float*)d_in[3];
    const float* W_ih0 = (const float*)d_in[4];
    const float* W_hh0 = (const float*)d_in[5];
    const float* b0    = (const float*)d_in[6];
    const float* W_ih1 = (const float*)d_in[7];
    const float* W_hh1 = (const float*)d_in[8];
    const float* b1    = (const float*)d_in[9];
    const float* lin_w = (const float*)d_in[10];
    const float* lin_b = (const float*)d_in[11];
    float* out = (float*)d_out;

    char* ws = (char*)d_ws;
    const size_t HBYTES = (size_t)BB * TT * HH * 2;  // 32 MB fp16 h0
    _Float16* h0g = (_Float16*)ws;
    int* flags    = (int*)(ws + HBYTES);             // 64*32 ints (poison-safe)
    float* pooled = (float*)(ws + HBYTES + 8192);

    k_pipe<<<dim3(2 * BB), dim3(512), 0, stream>>>(
        x, lens, ff_w, ff_b, W_ih0, W_hh0, b0, W_ih1, W_hh1, b1, h0g, flags, pooled);
    k_head<<<dim3(1), dim3(448), 0, stream>>>(pooled, lin_w, lin_b, out);
}

// Round 6
// 1417.699 us; speedup vs baseline: 1.2309x; 1.2309x over previous
//
#include <hip/hip_runtime.h>
#include <hip/hip_fp16.h>

#define TT 2048
#define BB 64
#define HH 128
#define GG 512   // 4H
#define CH 64    // chunk (timesteps per handshake)
#define NCH (TT / CH)

typedef _Float16 f16x8 __attribute__((ext_vector_type(8)));
typedef _Float16 f16x4 __attribute__((ext_vector_type(4)));
typedef float f32x4 __attribute__((ext_vector_type(4)));

__device__ __forceinline__ float sigm(float x) {
    return __builtin_amdgcn_rcpf(1.0f + __expf(-x));
}
__device__ __forceinline__ float tanh_f(float x) {
    return 1.0f - 2.0f * __builtin_amdgcn_rcpf(1.0f + __expf(2.0f * x));
}
// LDS-only barrier: no vmcnt drain (HIP __syncthreads drains all global ops).
__device__ __forceinline__ void bar_lds() {
    asm volatile("s_waitcnt lgkmcnt(0)\n\ts_barrier" ::: "memory");
}

__device__ __forceinline__ f16x8 load_frag(const float* rowp, int kt, int lh) {
    const float4* p4 = (const float4*)(rowp + kt * 32 + lh * 8);
    float4 a = p4[0], b = p4[1];
    f16x8 f;
    f[0] = (_Float16)a.x; f[1] = (_Float16)a.y; f[2] = (_Float16)a.z; f[3] = (_Float16)a.w;
    f[4] = (_Float16)b.x; f[5] = (_Float16)b.y; f[6] = (_Float16)b.z; f[7] = (_Float16)b.w;
    return f;
}

// Round 22: r21 head-fusion with the two correctness fixes from the r21
// post-mortem:
//  (1) head spin is poison-safe: `while (flag != 1)` — the harness re-poisons
//      the workspace with a NONZERO pattern between iterations, so `== 0`
//      spins exit immediately (this is why the chunk flags spin `!= ch+1`).
//  (2) pooled stores are NONTEMPORAL, mirroring the proven cross-XCD h0g
//      handoff (write-through past the producer XCD's non-coherent L2),
//      before the agent-scope release flag.
// Recurrence is the FROZEN 1332us champion (see r16..r20 post-mortems: step =
// 620cy MFMA-pipe + ~940cy sync/latency; every structural deviation measured
// worse). This round only removes the ~50us outside k_pipe.
__global__ __launch_bounds__(512, 1) void k_pipe(
    const float* __restrict__ x, const int* __restrict__ lengths,
    const float* __restrict__ ff_w, const float* __restrict__ ff_b,
    const float* __restrict__ W_ih0, const float* __restrict__ W_hh0,
    const float* __restrict__ b0, const float* __restrict__ W_ih1,
    const float* __restrict__ W_hh1, const float* __restrict__ b1,
    const float* __restrict__ lin_w, const float* __restrict__ lin_b,
    _Float16* __restrict__ h0g, int* __restrict__ flags,
    float* __restrict__ pooled, float* __restrict__ out) {
    const int tid = threadIdx.x;
    const int w = tid >> 6;
    const int lane = tid & 63;
    const int c = lane & 15;
    const int lh = lane >> 4;
    const int un = 16 * w + c;
    const bool ard = (c == 0);     // A-frag reader lanes (M=1 row 0)
    const bool wr16 = (lane < 16); // C row m=0 lanes (lh==0)
    const int HFLAG = BB * NCH;    // head flags live after the chunk flags

    __shared__ float xs[TT];                 // producer
    __shared__ _Float16 Hb0[2][HH];          // producer
    __shared__ _Float16 Hb1[2][HH];          // consumer
    __shared__ _Float16 Qs[CH][GG];          // consumer: chunk gates (64 KB)

    if (blockIdx.x == 2 * BB) {
        // ======================= HEAD: fused k_head =======================
        if (tid < BB) {
            int guard = 0;
            while (__hip_atomic_load(&flags[HFLAG + tid], __ATOMIC_ACQUIRE,
                                     __HIP_MEMORY_SCOPE_AGENT) != 1) {
                __builtin_amdgcn_s_sleep(16);
                if (++guard > (1 << 22)) break;  // hang guard
            }
        }
        __syncthreads();
        if (tid < 448) {  // 448 = 64*7
            const int b = tid / 7, cc = tid % 7;
            const float* p = pooled + b * 384;
            const float* wr = lin_w + cc * 384;
            float a0 = 0.f, a1 = 0.f, a2 = 0.f, a3 = 0.f;
#pragma unroll
            for (int k = 0; k < 384; k += 4) {
                a0 += p[k + 0] * wr[k + 0];
                a1 += p[k + 1] * wr[k + 1];
                a2 += p[k + 2] * wr[k + 2];
                a3 += p[k + 3] * wr[k + 3];
            }
            out[tid] = lin_b[cc] + ((a0 + a1) + (a2 + a3));
        }
    } else if (blockIdx.x < BB) {
        // ======================= PRODUCER: layer 0 =======================
        const int b = blockIdx.x;
        for (int i = tid; i < TT; i += 512) xs[i] = x[b * TT + i];
        if (tid < 2 * HH) ((_Float16*)Hb0)[tid] = (_Float16)0.f;

        f16x8 Bf[4][4];
        float v[4], u0[4];
#pragma unroll
        for (int t2 = 0; t2 < 4; ++t2) {
            const int r = t2 * HH + un;
#pragma unroll
            for (int kt = 0; kt < 4; ++kt) Bf[t2][kt] = load_frag(W_hh0 + r * HH, kt, lh);
            const float4* wi4 = (const float4*)(W_ih0 + r * HH);
            const float4* fw4 = (const float4*)ff_w;
            const float4* fb4 = (const float4*)ff_b;
            float vv = 0.f, uu = 0.f;
#pragma unroll
            for (int m = 0; m < HH / 4; ++m) {
                float4 a = wi4[m], fw = fw4[m], fb = fb4[m];
                vv += a.x * fw.x + a.y * fw.y + a.z * fw.z + a.w * fw.w;
                uu += a.x * fb.x + a.y * fb.y + a.z * fb.z + a.w * fb.w;
            }
            v[t2] = vv;
            u0[t2] = uu + b0[r];
        }
#pragma unroll
        for (int t2 = 0; t2 < 4; ++t2)
#pragma unroll
            for (int kt = 0; kt < 4; ++kt) asm volatile("" : "+v"(Bf[t2][kt]));

        float cst0 = 0.f;
        f16x8 av[4];
#pragma unroll
        for (int kt = 0; kt < 4; ++kt) av[kt] = (f16x8){0, 0, 0, 0, 0, 0, 0, 0};
        __syncthreads();

#define PSTEP(T_, RB_)                                                          \
    do {                                                                        \
        if (ard) {                                                              \
            _Pragma("unroll") for (int kt = 0; kt < 4; ++kt)                    \
                av[kt] = *(const f16x8*)&Hb0[RB_][kt * 32 + lh * 8];            \
        }                                                                       \
        const float xt = xs[T_];                                                \
        float p[4];                                                             \
        _Pragma("unroll") for (int t2 = 0; t2 < 4; ++t2) {                      \
            f32x4 alo, ahi;                                                     \
            const float ci = xt * v[t2] + u0[t2];                               \
            alo[0] = ci;  alo[1] = 0.f; alo[2] = 0.f; alo[3] = 0.f;             \
            ahi[0] = 0.f; ahi[1] = 0.f; ahi[2] = 0.f; ahi[3] = 0.f;             \
            alo = __builtin_amdgcn_mfma_f32_16x16x32_f16(av[0], Bf[t2][0],      \
                                                         alo, 0, 0, 0);         \
            ahi = __builtin_amdgcn_mfma_f32_16x16x32_f16(av[2], Bf[t2][2],      \
                                                         ahi, 0, 0, 0);         \
            alo = __builtin_amdgcn_mfma_f32_16x16x32_f16(av[1], Bf[t2][1],      \
                                                         alo, 0, 0, 0);         \
            ahi = __builtin_amdgcn_mfma_f32_16x16x32_f16(av[3], Bf[t2][3],      \
                                                         ahi, 0, 0, 0);         \
            p[t2] = alo[0] + ahi[0];                                            \
        }                                                                       \
        float gi = sigm(p[0]), gf = sigm(p[1]);                                 \
        float gg = tanh_f(p[2]), go = sigm(p[3]);                               \
        cst0 = gf * cst0 + gi * gg;                                             \
        float h0n = go * tanh_f(cst0);                                          \
        if (wr16) {                                                             \
            Hb0[(RB_) ^ 1][un] = (_Float16)h0n;                                 \
            __builtin_nontemporal_store(                                        \
                (_Float16)h0n, h0g + ((size_t)b * TT + (T_)) * HH + un);        \
        }                                                                       \
        bar_lds();                                                              \
    } while (0)

        for (int ch = 0; ch < NCH; ++ch) {
            const int t0 = ch * CH;
            for (int j = 0; j < CH; j += 2) {
                PSTEP(t0 + j, 0);
                PSTEP(t0 + j + 1, 1);
            }
            __syncthreads();  // drain every wave's h0 NT stores before signaling
            if (tid == 0)
                __hip_atomic_store(&flags[b * NCH + ch], ch + 1, __ATOMIC_RELEASE,
                                   __HIP_MEMORY_SCOPE_AGENT);
        }
#undef PSTEP
    } else {
        // ======================= CONSUMER: layer 1 =======================
        const int b = blockIdx.x - BB;
        if (tid < 2 * HH) ((_Float16*)Hb1)[tid] = (_Float16)0.f;

        f16x8 Bh[4][4];
        float bb1[4];
#pragma unroll
        for (int t2 = 0; t2 < 4; ++t2) {
#pragma unroll
            for (int kt = 0; kt < 4; ++kt)
                Bh[t2][kt] = load_frag(W_hh1 + (t2 * HH + un) * HH, kt, lh);
            bb1[t2] = b1[t2 * HH + un];
        }
#pragma unroll
        for (int t2 = 0; t2 < 4; ++t2)
#pragma unroll
            for (int kt = 0; kt < 4; ++kt) asm volatile("" : "+v"(Bh[t2][kt]));

        const int len = lengths[b];
        float cst1 = 0.f, mean = 0.f, mx = -1e30f, last = 0.f;
        f16x8 av[4];
#pragma unroll
        for (int kt = 0; kt < 4; ++kt) av[kt] = (f16x8){0, 0, 0, 0, 0, 0, 0, 0};
        __syncthreads();

#define CSTEP(T_, RB_)                                                          \
    do {                                                                        \
        const int jj = (T_) & (CH - 1);                                         \
        f16x4 qv = *(const f16x4*)&Qs[jj][un * 4]; /* all lanes: broadcast */   \
        if (ard) {                                                              \
            _Pragma("unroll") for (int kt = 0; kt < 4; ++kt)                    \
                av[kt] = *(const f16x8*)&Hb1[RB_][kt * 32 + lh * 8];            \
        }                                                                       \
        float p[4];                                                             \
        _Pragma("unroll") for (int t2 = 0; t2 < 4; ++t2) {                      \
            f32x4 alo, ahi;                                                     \
            alo[0] = (float)qv[t2];                                             \
            alo[1] = 0.f; alo[2] = 0.f; alo[3] = 0.f;                           \
            ahi[0] = 0.f; ahi[1] = 0.f; ahi[2] = 0.f; ahi[3] = 0.f;             \
            alo = __builtin_amdgcn_mfma_f32_16x16x32_f16(av[0], Bh[t2][0],      \
                                                         alo, 0, 0, 0);         \
            ahi = __builtin_amdgcn_mfma_f32_16x16x32_f16(av[2], Bh[t2][2],      \
                                                         ahi, 0, 0, 0);         \
            alo = __builtin_amdgcn_mfma_f32_16x16x32_f16(av[1], Bh[t2][1],      \
                                                         alo, 0, 0, 0);         \
            ahi = __builtin_amdgcn_mfma_f32_16x16x32_f16(av[3], Bh[t2][3],      \
                                                         ahi, 0, 0, 0);         \
            p[t2] = alo[0] + ahi[0];                                            \
        }                                                                       \
        float gi = sigm(p[0]), gf = sigm(p[1]);                                 \
        float gg = tanh_f(p[2]), go = sigm(p[3]);                               \
        cst1 = gf * cst1 + gi * gg;                                             \
        float h1n = go * tanh_f(cst1);                                          \
        if (wr16) Hb1[(RB_) ^ 1][un] = (_Float16)h1n;                           \
        if ((T_) < len) {                                                       \
            mean += h1n;                                                        \
            mx = fmaxf(mx, h1n);                                                \
        }                                                                       \
        if ((T_) == len - 1) last = h1n;                                        \
        bar_lds();                                                              \
    } while (0)

        for (int ch = 0; ch < NCH; ++ch) {
            if (tid == 0) {  // acquire gate
                int guard = 0;
                while (__hip_atomic_load(&flags[b * NCH + ch], __ATOMIC_ACQUIRE,
                                         __HIP_MEMORY_SCOPE_AGENT) != ch + 1) {
                    __builtin_amdgcn_s_sleep(8);
                    if (++guard > (1 << 22)) break;  // hang guard
                }
            }
            __syncthreads();
            // ---- chunk GEMM: Qs[j][un*4+t2] = b1 + W_ih1 . h0[t0+j] ----
            f16x8 Bi[4][4];  // reloaded per chunk (keeps step-loop pressure low)
#pragma unroll
            for (int t2 = 0; t2 < 4; ++t2)
#pragma unroll
                for (int kt = 0; kt < 4; ++kt)
                    Bi[t2][kt] = load_frag(W_ih1 + (t2 * HH + un) * HH, kt, lh);
            const _Float16* hbase = h0g + ((size_t)b * TT + ch * CH) * HH;
#pragma unroll
            for (int mt = 0; mt < 4; ++mt) {
                f16x8 am[4];  // A[m=c][k=kt*32+lh*8+j]
#pragma unroll
                for (int kt = 0; kt < 4; ++kt)
                    am[kt] = *(const f16x8*)(hbase + (mt * 16 + c) * HH + kt * 32 + lh * 8);
                f32x4 qa[4];
#pragma unroll
                for (int t2 = 0; t2 < 4; ++t2) {
                    qa[t2] = (f32x4){0.f, 0.f, 0.f, 0.f};
#pragma unroll
                    for (int kt = 0; kt < 4; ++kt)
                        qa[t2] = __builtin_amdgcn_mfma_f32_16x16x32_f16(
                            am[kt], Bi[t2][kt], qa[t2], 0, 0, 0);
                }
#pragma unroll
                for (int r = 0; r < 4; ++r) {  // C row m = 4*lh + r
                    f16x4 qv;
#pragma unroll
                    for (int t2 = 0; t2 < 4; ++t2) qv[t2] = (_Float16)(qa[t2][r] + bb1[t2]);
                    *(f16x4*)&Qs[mt * 16 + 4 * lh + r][un * 4] = qv;
                }
            }
            __syncthreads();  // Qs visible to all waves
            // ---- 64 recurrence steps, gates from LDS ----
            const int t0 = ch * CH;
            for (int j = 0; j < CH; j += 2) {
                CSTEP(t0 + j, 0);
                CSTEP(t0 + j + 1, 1);
            }
        }
#undef CSTEP
        if (wr16) {
            // Nontemporal: mirror the proven h0g cross-XCD handoff (write
            // through, don't park in this XCD's non-coherent L2).
            __builtin_nontemporal_store(mean / (float)len, pooled + b * 384 + un);
            __builtin_nontemporal_store(mx, pooled + b * 384 + 128 + un);
            __builtin_nontemporal_store(last, pooled + b * 384 + 256 + un);
        }
        __syncthreads();  // drain all waves' pooled stores (vmcnt 0)
        if (tid == 0)
            __hip_atomic_store(&flags[HFLAG + b], 1, __ATOMIC_RELEASE,
                               __HIP_MEMORY_SCOPE_AGENT);
    }
}

extern "C" void kernel_launch(void* const* d_in, const int* in_sizes, int n_in,
                              void* d_out, int out_size, void* d_ws, size_t ws_size,
                              hipStream_t stream) {
    const float* x     = (const float*)d_in[0];
    const int*   lens  = (const int*)d_in[1];
    const float* ff_w  = (const float*)d_in[2];
    const float* ff_b  = (const float*)d_in[3];
    const float* W_ih0 = (const float*)d_in[4];
    const float* W_hh0 = (const float*)d_in[5];
    const float* b0    = (const float*)d_in[6];
    const float* W_ih1 = (const float*)d_in[7];
    const float* W_hh1 = (const float*)d_in[8];
    const float* b1    = (const float*)d_in[9];
    const float* lin_w = (const float*)d_in[10];
    const float* lin_b = (const float*)d_in[11];
    float* out = (float*)d_out;

    char* ws = (char*)d_ws;
    const size_t HBYTES = (size_t)BB * TT * HH * 2;  // 32 MB fp16 h0
    _Float16* h0g = (_Float16*)ws;
    int* flags    = (int*)(ws + HBYTES);             // 64*32 chunk + 64 head flags
    float* pooled = (float*)(ws + HBYTES + 12288);

    k_pipe<<<dim3(2 * BB + 1), dim3(512), 0, stream>>>(
        x, lens, ff_w, ff_b, W_ih0, W_hh0, b0, W_ih1, W_hh1, b1, lin_w, lin_b,
        h0g, flags, pooled, out);
}

// Round 7
// 1391.566 us; speedup vs baseline: 1.2540x; 1.0188x over previous
//
#include <hip/hip_runtime.h>
#include <hip/hip_fp16.h>

#define TT 2048
#define BB 64
#define HH 128
#define GG 512   // 4H
#define CH 64    // chunk (timesteps per handshake)
#define NCH (TT / CH)

typedef _Float16 f16x8 __attribute__((ext_vector_type(8)));
typedef _Float16 f16x4 __attribute__((ext_vector_type(4)));
typedef float f32x4 __attribute__((ext_vector_type(4)));

__device__ __forceinline__ float sigm(float x) {
    return __builtin_amdgcn_rcpf(1.0f + __expf(-x));
}
__device__ __forceinline__ float tanh_f(float x) {
    return 1.0f - 2.0f * __builtin_amdgcn_rcpf(1.0f + __expf(2.0f * x));
}
// LDS-only barrier: no vmcnt drain (HIP __syncthreads drains all global ops).
__device__ __forceinline__ void bar_lds() {
    asm volatile("s_waitcnt lgkmcnt(0)\n\ts_barrier" ::: "memory");
}

__device__ __forceinline__ f16x8 load_frag(const float* rowp, int kt, int lh) {
    const float4* p4 = (const float4*)(rowp + kt * 32 + lh * 8);
    float4 a = p4[0], b = p4[1];
    f16x8 f;
    f[0] = (_Float16)a.x; f[1] = (_Float16)a.y; f[2] = (_Float16)a.z; f[3] = (_Float16)a.w;
    f[4] = (_Float16)b.x; f[5] = (_Float16)b.y; f[6] = (_Float16)b.z; f[7] = (_Float16)b.w;
    return f;
}

// Round 23: in-consumer head (r22 post-mortem: a dedicated head block cost a
// ~51us serial tail — it waited on all 64 consumers then did a latency-bound
// scalar GEMV against NT/HBM-resident pooled data; meanwhile fusion only
// saves ~15us of dispatch gap, the other ~34us is fixed graph overhead).
// Fix: each consumer block computes its OWN 7 outputs at the end, on
// LDS-resident pooled values (reusing the dead Qs buffer), waves 0-6 doing
// coalesced lin_w reads + a 64-lane shfl reduction. ~1-2us per block, fully
// parallel, no pooled buffer, no second handshake, no extra block.
// Recurrence/handshake byte-identical to the frozen 1332us champion
// (r17/r18/r19/r20 measured every structural deviation worse).
__global__ __launch_bounds__(512, 1) void k_pipe(
    const float* __restrict__ x, const int* __restrict__ lengths,
    const float* __restrict__ ff_w, const float* __restrict__ ff_b,
    const float* __restrict__ W_ih0, const float* __restrict__ W_hh0,
    const float* __restrict__ b0, const float* __restrict__ W_ih1,
    const float* __restrict__ W_hh1, const float* __restrict__ b1,
    const float* __restrict__ lin_w, const float* __restrict__ lin_b,
    _Float16* __restrict__ h0g, int* __restrict__ flags,
    float* __restrict__ out) {
    const int tid = threadIdx.x;
    const int w = tid >> 6;
    const int lane = tid & 63;
    const int c = lane & 15;
    const int lh = lane >> 4;
    const int un = 16 * w + c;
    const bool ard = (c == 0);     // A-frag reader lanes (M=1 row 0)
    const bool wr16 = (lane < 16); // C row m=0 lanes (lh==0)

    __shared__ float xs[TT];                 // producer
    __shared__ _Float16 Hb0[2][HH];          // producer
    __shared__ _Float16 Hb1[2][HH];          // consumer
    __shared__ _Float16 Qs[CH][GG];          // consumer: chunk gates (64 KB)

    if (blockIdx.x < BB) {
        // ======================= PRODUCER: layer 0 =======================
        const int b = blockIdx.x;
        for (int i = tid; i < TT; i += 512) xs[i] = x[b * TT + i];
        if (tid < 2 * HH) ((_Float16*)Hb0)[tid] = (_Float16)0.f;

        f16x8 Bf[4][4];
        float v[4], u0[4];
#pragma unroll
        for (int t2 = 0; t2 < 4; ++t2) {
            const int r = t2 * HH + un;
#pragma unroll
            for (int kt = 0; kt < 4; ++kt) Bf[t2][kt] = load_frag(W_hh0 + r * HH, kt, lh);
            const float4* wi4 = (const float4*)(W_ih0 + r * HH);
            const float4* fw4 = (const float4*)ff_w;
            const float4* fb4 = (const float4*)ff_b;
            float vv = 0.f, uu = 0.f;
#pragma unroll
            for (int m = 0; m < HH / 4; ++m) {
                float4 a = wi4[m], fw = fw4[m], fb = fb4[m];
                vv += a.x * fw.x + a.y * fw.y + a.z * fw.z + a.w * fw.w;
                uu += a.x * fb.x + a.y * fb.y + a.z * fb.z + a.w * fb.w;
            }
            v[t2] = vv;
            u0[t2] = uu + b0[r];
        }
#pragma unroll
        for (int t2 = 0; t2 < 4; ++t2)
#pragma unroll
            for (int kt = 0; kt < 4; ++kt) asm volatile("" : "+v"(Bf[t2][kt]));

        float cst0 = 0.f;
        f16x8 av[4];
#pragma unroll
        for (int kt = 0; kt < 4; ++kt) av[kt] = (f16x8){0, 0, 0, 0, 0, 0, 0, 0};
        __syncthreads();

#define PSTEP(T_, RB_)                                                          \
    do {                                                                        \
        if (ard) {                                                              \
            _Pragma("unroll") for (int kt = 0; kt < 4; ++kt)                    \
                av[kt] = *(const f16x8*)&Hb0[RB_][kt * 32 + lh * 8];            \
        }                                                                       \
        const float xt = xs[T_];                                                \
        float p[4];                                                             \
        _Pragma("unroll") for (int t2 = 0; t2 < 4; ++t2) {                      \
            f32x4 alo, ahi;                                                     \
            const float ci = xt * v[t2] + u0[t2];                               \
            alo[0] = ci;  alo[1] = 0.f; alo[2] = 0.f; alo[3] = 0.f;             \
            ahi[0] = 0.f; ahi[1] = 0.f; ahi[2] = 0.f; ahi[3] = 0.f;             \
            alo = __builtin_amdgcn_mfma_f32_16x16x32_f16(av[0], Bf[t2][0],      \
                                                         alo, 0, 0, 0);         \
            ahi = __builtin_amdgcn_mfma_f32_16x16x32_f16(av[2], Bf[t2][2],      \
                                                         ahi, 0, 0, 0);         \
            alo = __builtin_amdgcn_mfma_f32_16x16x32_f16(av[1], Bf[t2][1],      \
                                                         alo, 0, 0, 0);         \
            ahi = __builtin_amdgcn_mfma_f32_16x16x32_f16(av[3], Bf[t2][3],      \
                                                         ahi, 0, 0, 0);         \
            p[t2] = alo[0] + ahi[0];                                            \
        }                                                                       \
        float gi = sigm(p[0]), gf = sigm(p[1]);                                 \
        float gg = tanh_f(p[2]), go = sigm(p[3]);                               \
        cst0 = gf * cst0 + gi * gg;                                             \
        float h0n = go * tanh_f(cst0);                                          \
        if (wr16) {                                                             \
            Hb0[(RB_) ^ 1][un] = (_Float16)h0n;                                 \
            __builtin_nontemporal_store(                                        \
                (_Float16)h0n, h0g + ((size_t)b * TT + (T_)) * HH + un);        \
        }                                                                       \
        bar_lds();                                                              \
    } while (0)

        for (int ch = 0; ch < NCH; ++ch) {
            const int t0 = ch * CH;
            for (int j = 0; j < CH; j += 2) {
                PSTEP(t0 + j, 0);
                PSTEP(t0 + j + 1, 1);
            }
            __syncthreads();  // drain every wave's h0 NT stores before signaling
            if (tid == 0)
                __hip_atomic_store(&flags[b * NCH + ch], ch + 1, __ATOMIC_RELEASE,
                                   __HIP_MEMORY_SCOPE_AGENT);
        }
#undef PSTEP
    } else {
        // ======================= CONSUMER: layer 1 =======================
        const int b = blockIdx.x - BB;
        if (tid < 2 * HH) ((_Float16*)Hb1)[tid] = (_Float16)0.f;

        f16x8 Bh[4][4];
        float bb1[4];
#pragma unroll
        for (int t2 = 0; t2 < 4; ++t2) {
#pragma unroll
            for (int kt = 0; kt < 4; ++kt)
                Bh[t2][kt] = load_frag(W_hh1 + (t2 * HH + un) * HH, kt, lh);
            bb1[t2] = b1[t2 * HH + un];
        }
#pragma unroll
        for (int t2 = 0; t2 < 4; ++t2)
#pragma unroll
            for (int kt = 0; kt < 4; ++kt) asm volatile("" : "+v"(Bh[t2][kt]));

        const int len = lengths[b];
        float cst1 = 0.f, mean = 0.f, mx = -1e30f, last = 0.f;
        f16x8 av[4];
#pragma unroll
        for (int kt = 0; kt < 4; ++kt) av[kt] = (f16x8){0, 0, 0, 0, 0, 0, 0, 0};
        __syncthreads();

#define CSTEP(T_, RB_)                                                          \
    do {                                                                        \
        const int jj = (T_) & (CH - 1);                                         \
        f16x4 qv = *(const f16x4*)&Qs[jj][un * 4]; /* all lanes: broadcast */   \
        if (ard) {                                                              \
            _Pragma("unroll") for (int kt = 0; kt < 4; ++kt)                    \
                av[kt] = *(const f16x8*)&Hb1[RB_][kt * 32 + lh * 8];            \
        }                                                                       \
        float p[4];                                                             \
        _Pragma("unroll") for (int t2 = 0; t2 < 4; ++t2) {                      \
            f32x4 alo, ahi;                                                     \
            alo[0] = (float)qv[t2];                                             \
            alo[1] = 0.f; alo[2] = 0.f; alo[3] = 0.f;                           \
            ahi[0] = 0.f; ahi[1] = 0.f; ahi[2] = 0.f; ahi[3] = 0.f;             \
            alo = __builtin_amdgcn_mfma_f32_16x16x32_f16(av[0], Bh[t2][0],      \
                                                         alo, 0, 0, 0);         \
            ahi = __builtin_amdgcn_mfma_f32_16x16x32_f16(av[2], Bh[t2][2],      \
                                                         ahi, 0, 0, 0);         \
            alo = __builtin_amdgcn_mfma_f32_16x16x32_f16(av[1], Bh[t2][1],      \
                                                         alo, 0, 0, 0);         \
            ahi = __builtin_amdgcn_mfma_f32_16x16x32_f16(av[3], Bh[t2][3],      \
                                                         ahi, 0, 0, 0);         \
            p[t2] = alo[0] + ahi[0];                                            \
        }                                                                       \
        float gi = sigm(p[0]), gf = sigm(p[1]);                                 \
        float gg = tanh_f(p[2]), go = sigm(p[3]);                               \
        cst1 = gf * cst1 + gi * gg;                                             \
        float h1n = go * tanh_f(cst1);                                          \
        if (wr16) Hb1[(RB_) ^ 1][un] = (_Float16)h1n;                           \
        if ((T_) < len) {                                                       \
            mean += h1n;                                                        \
            mx = fmaxf(mx, h1n);                                                \
        }                                                                       \
        if ((T_) == len - 1) last = h1n;                                        \
        bar_lds();                                                              \
    } while (0)

        for (int ch = 0; ch < NCH; ++ch) {
            if (tid == 0) {  // acquire gate
                int guard = 0;
                while (__hip_atomic_load(&flags[b * NCH + ch], __ATOMIC_ACQUIRE,
                                         __HIP_MEMORY_SCOPE_AGENT) != ch + 1) {
                    __builtin_amdgcn_s_sleep(8);
                    if (++guard > (1 << 22)) break;  // hang guard
                }
            }
            __syncthreads();
            // ---- chunk GEMM: Qs[j][un*4+t2] = b1 + W_ih1 . h0[t0+j] ----
            f16x8 Bi[4][4];  // reloaded per chunk (keeps step-loop pressure low)
#pragma unroll
            for (int t2 = 0; t2 < 4; ++t2)
#pragma unroll
                for (int kt = 0; kt < 4; ++kt)
                    Bi[t2][kt] = load_frag(W_ih1 + (t2 * HH + un) * HH, kt, lh);
            const _Float16* hbase = h0g + ((size_t)b * TT + ch * CH) * HH;
#pragma unroll
            for (int mt = 0; mt < 4; ++mt) {
                f16x8 am[4];  // A[m=c][k=kt*32+lh*8+j]
#pragma unroll
                for (int kt = 0; kt < 4; ++kt)
                    am[kt] = *(const f16x8*)(hbase + (mt * 16 + c) * HH + kt * 32 + lh * 8);
                f32x4 qa[4];
#pragma unroll
                for (int t2 = 0; t2 < 4; ++t2) {
                    qa[t2] = (f32x4){0.f, 0.f, 0.f, 0.f};
#pragma unroll
                    for (int kt = 0; kt < 4; ++kt)
                        qa[t2] = __builtin_amdgcn_mfma_f32_16x16x32_f16(
                            am[kt], Bi[t2][kt], qa[t2], 0, 0, 0);
                }
#pragma unroll
                for (int r = 0; r < 4; ++r) {  // C row m = 4*lh + r
                    f16x4 qv;
#pragma unroll
                    for (int t2 = 0; t2 < 4; ++t2) qv[t2] = (_Float16)(qa[t2][r] + bb1[t2]);
                    *(f16x4*)&Qs[mt * 16 + 4 * lh + r][un * 4] = qv;
                }
            }
            __syncthreads();  // Qs visible to all waves
            // ---- 64 recurrence steps, gates from LDS ----
            const int t0 = ch * CH;
            for (int j = 0; j < CH; j += 2) {
                CSTEP(t0 + j, 0);
                CSTEP(t0 + j + 1, 1);
            }
        }
#undef CSTEP
        // ---- in-block head: out[b*7+cc] = lin_b[cc] + h . lin_w[cc] ----
        // h = [mean | mx | last] (384 floats) staged in the now-dead Qs LDS.
        float* hsm = (float*)Qs;
        if (wr16) {
            hsm[un] = mean / (float)len;
            hsm[128 + un] = mx;
            hsm[256 + un] = last;
        }
        __syncthreads();
        if (w < 7) {  // wave w computes output channel cc = w
            float s = 0.f;
#pragma unroll
            for (int j = 0; j < 6; ++j) {
                const int k = 64 * j + lane;  // coalesced lin_w, 2-way LDS bcast
                s += hsm[k] * lin_w[w * 384 + k];
            }
            s += __shfl_xor(s, 32);
            s += __shfl_xor(s, 16);
            s += __shfl_xor(s, 8);
            s += __shfl_xor(s, 4);
            s += __shfl_xor(s, 2);
            s += __shfl_xor(s, 1);
            if (lane == 0) out[b * 7 + w] = lin_b[w] + s;
        }
    }
}

extern "C" void kernel_launch(void* const* d_in, const int* in_sizes, int n_in,
                              void* d_out, int out_size, void* d_ws, size_t ws_size,
                              hipStream_t stream) {
    const float* x     = (const float*)d_in[0];
    const int*   lens  = (const int*)d_in[1];
    const float* ff_w  = (const float*)d_in[2];
    const float* ff_b  = (const float*)d_in[3];
    const float* W_ih0 = (const float*)d_in[4];
    const float* W_hh0 = (const float*)d_in[5];
    const float* b0    = (const float*)d_in[6];
    const float* W_ih1 = (const float*)d_in[7];
    const float* W_hh1 = (const float*)d_in[8];
    const float* b1    = (const float*)d_in[9];
    const float* lin_w = (const float*)d_in[10];
    const float* lin_b = (const float*)d_in[11];
    float* out = (float*)d_out;

    char* ws = (char*)d_ws;
    const size_t HBYTES = (size_t)BB * TT * HH * 2;  // 32 MB fp16 h0
    _Float16* h0g = (_Float16*)ws;
    int* flags    = (int*)(ws + HBYTES);             // 64*32 ints (poison-safe)

    k_pipe<<<dim3(2 * BB), dim3(512), 0, stream>>>(
        x, lens, ff_w, ff_b, W_ih0, W_hh0, b0, W_ih1, W_hh1, b1, lin_w, lin_b,
        h0g, flags, out);
}

// Round 10
// 1388.481 us; speedup vs baseline: 1.2568x; 1.0022x over previous
//
#include <hip/hip_runtime.h>
#include <hip/hip_fp16.h>

#define TT 2048
#define BB 64
#define HH 128
#define GG 512   // 4H
#define CH 64    // chunk (timesteps per handshake)
#define NCH (TT / CH)

typedef _Float16 f16x8 __attribute__((ext_vector_type(8)));
typedef _Float16 f16x4 __attribute__((ext_vector_type(4)));
typedef float f32x4 __attribute__((ext_vector_type(4)));

__device__ __forceinline__ float sigm(float x) {
    return __builtin_amdgcn_rcpf(1.0f + __expf(-x));
}
__device__ __forceinline__ float tanh_f(float x) {
    return 1.0f - 2.0f * __builtin_amdgcn_rcpf(1.0f + __expf(2.0f * x));
}
// LDS-only barrier: no vmcnt drain (HIP __syncthreads drains all global ops).
__device__ __forceinline__ void bar_lds() {
    asm volatile("s_waitcnt lgkmcnt(0)\n\ts_barrier" ::: "memory");
}

__device__ __forceinline__ f16x8 load_frag(const float* rowp, int kt, int lh) {
    const float4* p4 = (const float4*)(rowp + kt * 32 + lh * 8);
    float4 a = p4[0], b = p4[1];
    f16x8 f;
    f[0] = (_Float16)a.x; f[1] = (_Float16)a.y; f[2] = (_Float16)a.z; f[3] = (_Float16)a.w;
    f[4] = (_Float16)b.x; f[5] = (_Float16)b.y; f[6] = (_Float16)b.z; f[7] = (_Float16)b.w;
    return f;
}

// Round 26 == Round 24/25 resubmitted (both prior attempts were broker infra
// failures during acquire; source audit found no hang mechanism in the diff:
// +1.5KB LDS, tail writes hsm instead of aliasing Qs, no new barriers/spins).
// Theory unchanged: r23's +21us dispatch regression came from float-aliasing
// the CSTEP-hot Qs LDS array in the head tail (alias-analysis degradation in
// the main loop), not the tail's ~1-2us of arithmetic. Fix: dedicated
// __shared__ float hsm[384]; Qs stays f16-only. Hot loops byte-identical to
// the frozen 1332.6us champion. Endgame arithmetic: total ~= 1332.6 + ~1.5
// (tail) + ~38 (fixed graph overhead) ~= 1372us.
__global__ __launch_bounds__(512, 1) void k_pipe(
    const float* __restrict__ x, const int* __restrict__ lengths,
    const float* __restrict__ ff_w, const float* __restrict__ ff_b,
    const float* __restrict__ W_ih0, const float* __restrict__ W_hh0,
    const float* __restrict__ b0, const float* __restrict__ W_ih1,
    const float* __restrict__ W_hh1, const float* __restrict__ b1,
    const float* __restrict__ lin_w, const float* __restrict__ lin_b,
    _Float16* __restrict__ h0g, int* __restrict__ flags,
    float* __restrict__ out) {
    const int tid = threadIdx.x;
    const int w = tid >> 6;
    const int lane = tid & 63;
    const int c = lane & 15;
    const int lh = lane >> 4;
    const int un = 16 * w + c;
    const bool ard = (c == 0);     // A-frag reader lanes (M=1 row 0)
    const bool wr16 = (lane < 16); // C row m=0 lanes (lh==0)

    __shared__ float xs[TT];                 // producer
    __shared__ _Float16 Hb0[2][HH];          // producer
    __shared__ _Float16 Hb1[2][HH];          // consumer
    __shared__ _Float16 Qs[CH][GG];          // consumer: chunk gates (64 KB)
    __shared__ float hsm[3 * HH];            // consumer: pooled stage (1.5 KB)

    if (blockIdx.x < BB) {
        // ======================= PRODUCER: layer 0 =======================
        const int b = blockIdx.x;
        for (int i = tid; i < TT; i += 512) xs[i] = x[b * TT + i];
        if (tid < 2 * HH) ((_Float16*)Hb0)[tid] = (_Float16)0.f;

        f16x8 Bf[4][4];
        float v[4], u0[4];
#pragma unroll
        for (int t2 = 0; t2 < 4; ++t2) {
            const int r = t2 * HH + un;
#pragma unroll
            for (int kt = 0; kt < 4; ++kt) Bf[t2][kt] = load_frag(W_hh0 + r * HH, kt, lh);
            const float4* wi4 = (const float4*)(W_ih0 + r * HH);
            const float4* fw4 = (const float4*)ff_w;
            const float4* fb4 = (const float4*)ff_b;
            float vv = 0.f, uu = 0.f;
#pragma unroll
            for (int m = 0; m < HH / 4; ++m) {
                float4 a = wi4[m], fw = fw4[m], fb = fb4[m];
                vv += a.x * fw.x + a.y * fw.y + a.z * fw.z + a.w * fw.w;
                uu += a.x * fb.x + a.y * fb.y + a.z * fb.z + a.w * fb.w;
            }
            v[t2] = vv;
            u0[t2] = uu + b0[r];
        }
#pragma unroll
        for (int t2 = 0; t2 < 4; ++t2)
#pragma unroll
            for (int kt = 0; kt < 4; ++kt) asm volatile("" : "+v"(Bf[t2][kt]));

        float cst0 = 0.f;
        f16x8 av[4];
#pragma unroll
        for (int kt = 0; kt < 4; ++kt) av[kt] = (f16x8){0, 0, 0, 0, 0, 0, 0, 0};
        __syncthreads();

#define PSTEP(T_, RB_)                                                          \
    do {                                                                        \
        if (ard) {                                                              \
            _Pragma("unroll") for (int kt = 0; kt < 4; ++kt)                    \
                av[kt] = *(const f16x8*)&Hb0[RB_][kt * 32 + lh * 8];            \
        }                                                                       \
        const float xt = xs[T_];                                                \
        float p[4];                                                             \
        _Pragma("unroll") for (int t2 = 0; t2 < 4; ++t2) {                      \
            f32x4 alo, ahi;                                                     \
            const float ci = xt * v[t2] + u0[t2];                               \
            alo[0] = ci;  alo[1] = 0.f; alo[2] = 0.f; alo[3] = 0.f;             \
            ahi[0] = 0.f; ahi[1] = 0.f; ahi[2] = 0.f; ahi[3] = 0.f;             \
            alo = __builtin_amdgcn_mfma_f32_16x16x32_f16(av[0], Bf[t2][0],      \
                                                         alo, 0, 0, 0);         \
            ahi = __builtin_amdgcn_mfma_f32_16x16x32_f16(av[2], Bf[t2][2],      \
                                                         ahi, 0, 0, 0);         \
            alo = __builtin_amdgcn_mfma_f32_16x16x32_f16(av[1], Bf[t2][1],      \
                                                         alo, 0, 0, 0);         \
            ahi = __builtin_amdgcn_mfma_f32_16x16x32_f16(av[3], Bf[t2][3],      \
                                                         ahi, 0, 0, 0);         \
            p[t2] = alo[0] + ahi[0];                                            \
        }                                                                       \
        float gi = sigm(p[0]), gf = sigm(p[1]);                                 \
        float gg = tanh_f(p[2]), go = sigm(p[3]);                               \
        cst0 = gf * cst0 + gi * gg;                                             \
        float h0n = go * tanh_f(cst0);                                          \
        if (wr16) {                                                             \
            Hb0[(RB_) ^ 1][un] = (_Float16)h0n;                                 \
            __builtin_nontemporal_store(                                        \
                (_Float16)h0n, h0g + ((size_t)b * TT + (T_)) * HH + un);        \
        }                                                                       \
        bar_lds();                                                              \
    } while (0)

        for (int ch = 0; ch < NCH; ++ch) {
            const int t0 = ch * CH;
            for (int j = 0; j < CH; j += 2) {
                PSTEP(t0 + j, 0);
                PSTEP(t0 + j + 1, 1);
            }
            __syncthreads();  // drain every wave's h0 NT stores before signaling
            if (tid == 0)
                __hip_atomic_store(&flags[b * NCH + ch], ch + 1, __ATOMIC_RELEASE,
                                   __HIP_MEMORY_SCOPE_AGENT);
        }
#undef PSTEP
    } else {
        // ======================= CONSUMER: layer 1 =======================
        const int b = blockIdx.x - BB;
        if (tid < 2 * HH) ((_Float16*)Hb1)[tid] = (_Float16)0.f;

        f16x8 Bh[4][4];
        float bb1[4];
#pragma unroll
        for (int t2 = 0; t2 < 4; ++t2) {
#pragma unroll
            for (int kt = 0; kt < 4; ++kt)
                Bh[t2][kt] = load_frag(W_hh1 + (t2 * HH + un) * HH, kt, lh);
            bb1[t2] = b1[t2 * HH + un];
        }
#pragma unroll
        for (int t2 = 0; t2 < 4; ++t2)
#pragma unroll
            for (int kt = 0; kt < 4; ++kt) asm volatile("" : "+v"(Bh[t2][kt]));

        const int len = lengths[b];
        float cst1 = 0.f, mean = 0.f, mx = -1e30f, last = 0.f;
        f16x8 av[4];
#pragma unroll
        for (int kt = 0; kt < 4; ++kt) av[kt] = (f16x8){0, 0, 0, 0, 0, 0, 0, 0};
        __syncthreads();

#define CSTEP(T_, RB_)                                                          \
    do {                                                                        \
        const int jj = (T_) & (CH - 1);                                         \
        f16x4 qv = *(const f16x4*)&Qs[jj][un * 4]; /* all lanes: broadcast */   \
        if (ard) {                                                              \
            _Pragma("unroll") for (int kt = 0; kt < 4; ++kt)                    \
                av[kt] = *(const f16x8*)&Hb1[RB_][kt * 32 + lh * 8];            \
        }                                                                       \
        float p[4];                                                             \
        _Pragma("unroll") for (int t2 = 0; t2 < 4; ++t2) {                      \
            f32x4 alo, ahi;                                                     \
            alo[0] = (float)qv[t2];                                             \
            alo[1] = 0.f; alo[2] = 0.f; alo[3] = 0.f;                           \
            ahi[0] = 0.f; ahi[1] = 0.f; ahi[2] = 0.f; ahi[3] = 0.f;             \
            alo = __builtin_amdgcn_mfma_f32_16x16x32_f16(av[0], Bh[t2][0],      \
                                                         alo, 0, 0, 0);         \
            ahi = __builtin_amdgcn_mfma_f32_16x16x32_f16(av[2], Bh[t2][2],      \
                                                         ahi, 0, 0, 0);         \
            alo = __builtin_amdgcn_mfma_f32_16x16x32_f16(av[1], Bh[t2][1],      \
                                                         alo, 0, 0, 0);         \
            ahi = __builtin_amdgcn_mfma_f32_16x16x32_f16(av[3], Bh[t2][3],      \
                                                         ahi, 0, 0, 0);         \
            p[t2] = alo[0] + ahi[0];                                            \
        }                                                                       \
        float gi = sigm(p[0]), gf = sigm(p[1]);                                 \
        float gg = tanh_f(p[2]), go = sigm(p[3]);                               \
        cst1 = gf * cst1 + gi * gg;                                             \
        float h1n = go * tanh_f(cst1);                                          \
        if (wr16) Hb1[(RB_) ^ 1][un] = (_Float16)h1n;                           \
        if ((T_) < len) {                                                       \
            mean += h1n;                                                        \
            mx = fmaxf(mx, h1n);                                                \
        }                                                                       \
        if ((T_) == len - 1) last = h1n;                                        \
        bar_lds();                                                              \
    } while (0)

        for (int ch = 0; ch < NCH; ++ch) {
            if (tid == 0) {  // acquire gate
                int guard = 0;
                while (__hip_atomic_load(&flags[b * NCH + ch], __ATOMIC_ACQUIRE,
                                         __HIP_MEMORY_SCOPE_AGENT) != ch + 1) {
                    __builtin_amdgcn_s_sleep(8);
                    if (++guard > (1 << 22)) break;  // hang guard
                }
            }
            __syncthreads();
            // ---- chunk GEMM: Qs[j][un*4+t2] = b1 + W_ih1 . h0[t0+j] ----
            f16x8 Bi[4][4];  // reloaded per chunk (keeps step-loop pressure low)
#pragma unroll
            for (int t2 = 0; t2 < 4; ++t2)
#pragma unroll
                for (int kt = 0; kt < 4; ++kt)
                    Bi[t2][kt] = load_frag(W_ih1 + (t2 * HH + un) * HH, kt, lh);
            const _Float16* hbase = h0g + ((size_t)b * TT + ch * CH) * HH;
#pragma unroll
            for (int mt = 0; mt < 4; ++mt) {
                f16x8 am[4];  // A[m=c][k=kt*32+lh*8+j]
#pragma unroll
                for (int kt = 0; kt < 4; ++kt)
                    am[kt] = *(const f16x8*)(hbase + (mt * 16 + c) * HH + kt * 32 + lh * 8);
                f32x4 qa[4];
#pragma unroll
                for (int t2 = 0; t2 < 4; ++t2) {
                    qa[t2] = (f32x4){0.f, 0.f, 0.f, 0.f};
#pragma unroll
                    for (int kt = 0; kt < 4; ++kt)
                        qa[t2] = __builtin_amdgcn_mfma_f32_16x16x32_f16(
                            am[kt], Bi[t2][kt], qa[t2], 0, 0, 0);
                }
#pragma unroll
                for (int r = 0; r < 4; ++r) {  // C row m = 4*lh + r
                    f16x4 qv;
#pragma unroll
                    for (int t2 = 0; t2 < 4; ++t2) qv[t2] = (_Float16)(qa[t2][r] + bb1[t2]);
                    *(f16x4*)&Qs[mt * 16 + 4 * lh + r][un * 4] = qv;
                }
            }
            __syncthreads();  // Qs visible to all waves
            // ---- 64 recurrence steps, gates from LDS ----
            const int t0 = ch * CH;
            for (int j = 0; j < CH; j += 2) {
                CSTEP(t0 + j, 0);
                CSTEP(t0 + j + 1, 1);
            }
        }
#undef CSTEP
        // ---- in-block head: out[b*7+cc] = lin_b[cc] + h . lin_w[cc] ----
        // h = [mean | mx | last] staged in a DEDICATED float LDS buffer
        // (hsm), so Qs keeps a single (f16) access type in the hot loop.
        if (wr16) {
            hsm[un] = mean / (float)len;
            hsm[128 + un] = mx;
            hsm[256 + un] = last;
        }
        __syncthreads();
        if (w < 7) {  // wave w computes output channel cc = w
            float s = 0.f;
#pragma unroll
            for (int j = 0; j < 6; ++j) {
                const int k = 64 * j + lane;  // coalesced lin_w, 2-way LDS bcast
                s += hsm[k] * lin_w[w * 384 + k];
            }
            s += __shfl_xor(s, 32);
            s += __shfl_xor(s, 16);
            s += __shfl_xor(s, 8);
            s += __shfl_xor(s, 4);
            s += __shfl_xor(s, 2);
            s += __shfl_xor(s, 1);
            if (lane == 0) out[b * 7 + w] = lin_b[w] + s;
        }
    }
}

extern "C" void kernel_launch(void* const* d_in, const int* in_sizes, int n_in,
                              void* d_out, int out_size, void* d_ws, size_t ws_size,
                              hipStream_t stream) {
    const float* x     = (const float*)d_in[0];
    const int*   lens  = (const int*)d_in[1];
    const float* ff_w  = (const float*)d_in[2];
    const float* ff_b  = (const float*)d_in[3];
    const float* W_ih0 = (const float*)d_in[4];
    const float* W_hh0 = (const float*)d_in[5];
    const float* b0    = (const float*)d_in[6];
    const float* W_ih1 = (const float*)d_in[7];
    const float* W_hh1 = (const float*)d_in[8];
    const float* b1    = (const float*)d_in[9];
    const float* lin_w = (const float*)d_in[10];
    const float* lin_b = (const float*)d_in[11];
    float* out = (float*)d_out;

    char* ws = (char*)d_ws;
    const size_t HBYTES = (size_t)BB * TT * HH * 2;  // 32 MB fp16 h0
    _Float16* h0g = (_Float16*)ws;
    int* flags    = (int*)(ws + HBYTES);             // 64*32 ints (poison-safe)

    k_pipe<<<dim3(2 * BB), dim3(512), 0, stream>>>(
        x, lens, ff_w, ff_b, W_ih0, W_hh0, b0, W_ih1, W_hh1, b1, lin_w, lin_b,
        h0g, flags, out);
}